// Round 1
// baseline (42.477 us; speedup 1.0000x reference)
//
#include <hip/hip_runtime.h>

// Cubic Hermite spline fwd (nsf cubic_spline, inverse=False), elementwise.
// One thread per element; all K=16 loops fully unrolled (static register
// indexing only — no runtime-indexed arrays, so nothing spills to scratch).
// Bin selection is a monotone scan with cndmask selects, shared between
// x_lower and x_upper (params identical for both evaluations).

namespace {

constexpr int K = 16;
constexpr float MBW = 0.001f;  // MIN_BIN_WIDTH
constexpr float MBH = 0.001f;  // MIN_BIN_HEIGHT

__device__ __forceinline__ float frcp(float x) { return __builtin_amdgcn_rcpf(x); }
__device__ __forceinline__ float fsgn(float v) { return (v > 0.f) ? 1.f : ((v < 0.f) ? -1.f : 0.f); }
__device__ __forceinline__ float fsigmoid(float x) { return frcp(1.f + __expf(-x)); }

__global__ __launch_bounds__(256) void cubic_spline_fwd_kernel(
    const float* __restrict__ xlo,
    const float* __restrict__ xup,
    const float* __restrict__ params,
    float* __restrict__ out,
    int N)
{
    const int i = blockIdx.x * 256 + threadIdx.x;
    if (i >= N) return;

    // ---- load 34 params (byte offset i*136 is 8B-aligned -> float2) ----
    const float2* p2 = reinterpret_cast<const float2*>(params + (size_t)i * (2 * K + 2));
    float uw[K], uh[K];
    float2 buf;
    #pragma unroll
    for (int j = 0; j < 8; ++j) {
        buf = p2[j];
        uw[2 * j] = buf.x; uw[2 * j + 1] = buf.y;
    }
    #pragma unroll
    for (int j = 0; j < 8; ++j) {
        buf = p2[8 + j];
        uh[2 * j] = buf.x; uh[2 * j + 1] = buf.y;
    }
    buf = p2[16];
    const float udl = buf.x, udr = buf.y;

    const float x0 = xlo[i];
    const float x1 = xup[i];

    // ---- softmax over widths & heights ----
    float mw = uw[0], mh = uh[0];
    #pragma unroll
    for (int j = 1; j < K; ++j) { mw = fmaxf(mw, uw[j]); mh = fmaxf(mh, uh[j]); }

    float w[K], h[K];
    float sw = 0.f, sh = 0.f;
    #pragma unroll
    for (int j = 0; j < K; ++j) {
        w[j] = __expf(uw[j] - mw); sw += w[j];
        h[j] = __expf(uh[j] - mh); sh += h[j];
    }
    const float cw_scale = (1.0f - MBW * K) * frcp(sw);
    const float ch_scale = (1.0f - MBH * K) * frcp(sh);

    float s[K], rw[K];
    #pragma unroll
    for (int j = 0; j < K; ++j) {
        w[j] = MBW + w[j] * cw_scale;
        h[j] = MBH + h[j] * ch_scale;
        rw[j] = frcp(w[j]);
        s[j] = h[j] * rw[j];
    }

    // ---- Hermite derivatives at the K+1 knots ----
    float dv[K + 1];
    dv[0] = fsigmoid(udl) * 3.f * s[0];
    dv[K] = fsigmoid(udr) * 3.f * s[K - 1];
    #pragma unroll
    for (int j = 1; j < K; ++j) {
        const float s0 = s[j - 1], s1 = s[j];
        const float w0 = w[j - 1], w1 = w[j];
        const float min1 = fminf(fabsf(s0), fabsf(s1));
        const float min2 = 0.5f * (w1 * s0 + w0 * s1) * frcp(w0 + w1);
        dv[j] = fminf(min1, min2) * (fsgn(s0) + fsgn(s1));
    }

    // ---- static scan over bins: last bin with knot <= x wins ----
    // knots: cw(j) = sum_{m<j} w[m]; x in [0,1) so bin 0 condition always
    // true at j=0 and the final knot (==1) is never crossed.
    float cw = 0.f, ch = 0.f;
    float a0 = 0.f, b0 = 0.f, c0 = 0.f, d0 = 0.f, l0 = 0.f;
    float a1 = 0.f, b1 = 0.f, c1 = 0.f, d1 = 0.f, l1 = 0.f;
    #pragma unroll
    for (int j = 0; j < K; ++j) {
        const float aj = (dv[j] + dv[j + 1] - 2.f * s[j]) * (rw[j] * rw[j]);
        const float bj = (3.f * s[j] - 2.f * dv[j] - dv[j + 1]) * rw[j];
        const float cj = dv[j];
        const float dj = ch;
        const bool t0 = (j == 0) | (x0 >= cw);
        const bool t1 = (j == 0) | (x1 >= cw);
        a0 = t0 ? aj : a0; b0 = t0 ? bj : b0; c0 = t0 ? cj : c0;
        d0 = t0 ? dj : d0; l0 = t0 ? cw : l0;
        a1 = t1 ? aj : a1; b1 = t1 ? bj : b1; c1 = t1 ? cj : c1;
        d1 = t1 ? dj : d1; l1 = t1 ? cw : l1;
        cw += w[j];
        ch += h[j];
    }

    float t = x0 - l0;
    const float z0 = ((a0 * t + b0) * t + c0) * t + d0;
    t = x1 - l1;
    const float z1 = ((a1 * t + b1) * t + c1) * t + d1;

    out[i]     = fminf(fmaxf(z0, 0.f), 1.f);
    out[N + i] = fminf(fmaxf(z1, 0.f), 1.f);
}

}  // namespace

extern "C" void kernel_launch(void* const* d_in, const int* in_sizes, int n_in,
                              void* d_out, int out_size, void* d_ws, size_t ws_size,
                              hipStream_t stream) {
    const float* xlo    = (const float*)d_in[0];
    const float* xup    = (const float*)d_in[1];
    const float* params = (const float*)d_in[2];
    float* out = (float*)d_out;
    const int N = in_sizes[0];

    const int block = 256;
    const int grid = (N + block - 1) / block;
    cubic_spline_fwd_kernel<<<grid, block, 0, stream>>>(xlo, xup, params, out, N);
}